// Round 8
// baseline (188.068 us; speedup 1.0000x reference)
//
#include <hip/hip_runtime.h>
#include <hip/hip_bf16.h>
#include <cstdint>
#include <cstddef>

// Sizes fixed by the reference problem.
#define DMODEL 1024
#define BATCH  4
#define SEQ    4096
#define BSROWS (BATCH*SEQ)     // 16384
#define CHUNK  32
#define NCHUNK (SEQ/CHUNK)     // 128
#define NCH_T  (BATCH*NCHUNK)  // 512 total chunks

typedef __attribute__((ext_vector_type(8))) short bf16x8;
typedef __attribute__((ext_vector_type(4))) float f32x4;

// ---- helpers ---------------------------------------------------------------

__device__ __forceinline__ unsigned short f2bf(float f) {
  union { float f; uint32_t u; } v; v.f = f;
  uint32_t u = v.u;
  u += 0x7FFFu + ((u >> 16) & 1u);   // round-to-nearest-even
  return (unsigned short)(u >> 16);
}

__device__ __forceinline__ float sigmoid_dev(const float* dp) {
  return 1.0f / (1.0f + expf(-dp[0]));
}

typedef __attribute__((address_space(1))) void void_g;
typedef __attribute__((address_space(3))) void void_l;

__device__ __forceinline__ void gl2lds16(const void* g, void* l) {
  __builtin_amdgcn_global_load_lds((void_g*)g, (void_l*)l, 16, 0, 0);
}

// ---- 64x64-tile NT K-loop (BK=64, XOR-8 swizzle) — used by mid2 ------------
// Ring-3 LDS pipeline, counted vmcnt(4), raw s_barrier, 1 barrier per K-step.
__device__ __forceinline__ void kloop64(
    const unsigned short* __restrict__ A, const unsigned short* __restrict__ B,
    int m0, int n0, f32x4 acc[2][2],
    unsigned short* As, unsigned short* Bs, int tid) {
  int lane = tid & 63, w = tid >> 6, wm = w & 1, wn = w >> 1;
  int quad = lane >> 4, l16 = lane & 15;
  int r = tid >> 3, cch = tid & 7;
  int g = cch ^ (r & 7);

  auto stage = [&](int t, int slot) {
    int k0 = t * 64;
    unsigned short* dA = As + slot * 4096;
    unsigned short* dB = Bs + slot * 4096;
    gl2lds16(A + (size_t)(m0 + r) * DMODEL + k0 + g * 8,      dA + r * 64 + cch * 8);
    gl2lds16(A + (size_t)(m0 + 32 + r) * DMODEL + k0 + g * 8, dA + (32 + r) * 64 + cch * 8);
    gl2lds16(B + (size_t)(n0 + r) * DMODEL + k0 + g * 8,      dB + r * 64 + cch * 8);
    gl2lds16(B + (size_t)(n0 + 32 + r) * DMODEL + k0 + g * 8, dB + (32 + r) * 64 + cch * 8);
  };
  auto compute = [&](int slot) {
    const bf16x8* Av = (const bf16x8*)(As + slot * 4096);
    const bf16x8* Bv = (const bf16x8*)(Bs + slot * 4096);
    #pragma unroll
    for (int kk = 0; kk < 2; ++kk) {
      bf16x8 af[2], bfr[2];
      #pragma unroll
      for (int i = 0; i < 2; ++i) {
        int rowA = wm * 32 + i * 16 + l16;
        af[i]  = Av[rowA * 8 + ((kk * 4 + quad) ^ (l16 & 7))];
        int rowB = wn * 32 + i * 16 + l16;
        bfr[i] = Bv[rowB * 8 + ((kk * 4 + quad) ^ (l16 & 7))];
      }
      __builtin_amdgcn_s_setprio(1);
      #pragma unroll
      for (int i = 0; i < 2; ++i)
        #pragma unroll
        for (int j = 0; j < 2; ++j)
          acc[i][j] = __builtin_amdgcn_mfma_f32_16x16x32_bf16(af[i], bfr[j], acc[i][j], 0, 0, 0);
      __builtin_amdgcn_s_setprio(0);
    }
  };

  stage(0, 0); stage(1, 1);
  asm volatile("s_waitcnt vmcnt(4)" ::: "memory");
  __builtin_amdgcn_s_barrier();
  asm volatile("" ::: "memory");
  int cur = 0;
  for (int t = 0; t < 14; ++t) {
    int ns = cur + 2; if (ns >= 3) ns -= 3;
    stage(t + 2, ns);
    compute(cur);
    asm volatile("s_waitcnt vmcnt(4)" ::: "memory");
    __builtin_amdgcn_s_barrier();
    asm volatile("" ::: "memory");
    cur = (cur == 2) ? 0 : cur + 1;
  }
  compute(cur);                                        // tile 14
  asm volatile("s_waitcnt vmcnt(0)" ::: "memory");
  __builtin_amdgcn_s_barrier();
  asm volatile("" ::: "memory");
  cur = (cur == 2) ? 0 : cur + 1;
  compute(cur);                                        // tile 15
}

// ---- prep_scan: 512 blocks, one 32-row chunk each --------------------------
// Single-pass local scan: hv (bf16) + carry (f32), explicit depth-2 load
// prefetch, beta local scans folded in (predicated register-only unroll).
__global__ __launch_bounds__(256) void prep_scan(
    const float* __restrict__ x, const float* __restrict__ mask,
    const float* __restrict__ dp,
    unsigned short* __restrict__ hv, float* __restrict__ carry,
    float* __restrict__ lbeta, float* __restrict__ cbeta) {
  int blk = blockIdx.x;
  int tid = threadIdx.x;
  float decay = sigmoid_dev(dp);
  int b = blk / NCHUNK, c = blk % NCHUNK;
  int base = b * SEQ + c * CHUNK;
  const float4* xp = (const float4*)(x + (size_t)base * DMODEL);
  const float4* mp4 = (const float4*)(mask + base);
  float mreg[32];
  #pragma unroll
  for (int q = 0; q < 8; ++q) {
    float4 t = mp4[q];
    mreg[q * 4 + 0] = t.x; mreg[q * 4 + 1] = t.y;
    mreg[q * 4 + 2] = t.z; mreg[q * 4 + 3] = t.w;
  }

  // beta scan, register-only: lane tid<32 ends with the scan value at row tid.
  {
    float hb = 0.f;
    #pragma unroll
    for (int i = 0; i < 32; ++i) {
      float nv = decay * hb + mreg[i];
      hb = (tid >= i) ? nv : hb;
    }
    if (tid < 32) {
      lbeta[base + tid] = hb;
      if (tid == 31) cbeta[base >> 5] = hb;
    }
  }

  // main scan with rolling 2-deep prefetch
  float4 x0 = xp[tid];
  float4 x1 = xp[256 + tid];
  float4 h = make_float4(0.f, 0.f, 0.f, 0.f);
  #pragma unroll
  for (int s = 0; s < CHUNK; ++s) {
    float4 cur = x0;
    x0 = x1;
    if (s + 2 < CHUNK) x1 = xp[(size_t)(s + 2) * 256 + tid];
    float m = mreg[s];
    h.x = decay * h.x + m * cur.x;
    h.y = decay * h.y + m * cur.y;
    h.z = decay * h.z + m * cur.z;
    h.w = decay * h.w + m * cur.w;
    ushort4 o;
    o.x = f2bf(h.x); o.y = f2bf(h.y); o.z = f2bf(h.z); o.w = f2bf(h.w);
    ((ushort4*)hv)[(size_t)(base + s) * 256 + tid] = o;
  }
  ((float4*)carry)[(size_t)blk * 256 + tid] = h;
}

// ---- prep_misc: 1280 blocks ------------------------------------------------
// blocks [0,256)    : W_f rows 4e..4e+3 -> bf16 + bb[e]=dot(W_f[e],b_up).
//                     One wave per row; FIX(r8): 4 strided float4 passes per
//                     lane (q*64+lane) cover the FULL 1024-elem row (r7 bug:
//                     only row4[lane] = first quarter -> absmax 2.0).
// blocks [256,1280) : W_up f32 [c][d] -> bf16 transposed [d][c] (ushort4 store)
__global__ __launch_bounds__(256) void prep_misc(
    const float* __restrict__ W_up, const float* __restrict__ b_up,
    const float* __restrict__ W_f,
    unsigned short* __restrict__ Wf_bf, unsigned short* __restrict__ WupT,
    float* __restrict__ bb) {
  __shared__ float tile[32][33];
  int blk = blockIdx.x;
  int tid = threadIdx.x;
  if (blk < 256) {
    int w = tid >> 6, lane = tid & 63;
    int e = blk * 4 + w;                        // one row per wave
    const float4* row4 = (const float4*)(W_f + (size_t)e * DMODEL);
    const float4* bup4 = (const float4*)b_up;
    ushort4* out4 = (ushort4*)(Wf_bf + (size_t)e * DMODEL);
    float s = 0.f;
    #pragma unroll
    for (int q = 0; q < 4; ++q) {
      float4 v  = row4[q * 64 + lane];
      float4 bu = bup4[q * 64 + lane];
      ushort4 o;
      o.x = f2bf(v.x); o.y = f2bf(v.y); o.z = f2bf(v.z); o.w = f2bf(v.w);
      out4[q * 64 + lane] = o;
      s += v.x * bu.x + v.y * bu.y + v.z * bu.z + v.w * bu.w;
    }
    #pragma unroll
    for (int off = 32; off; off >>= 1) s += __shfl_down(s, off);
    if (lane == 0) bb[e] = s;
  } else {
    int id = blk - 256;
    int bx = id & 31, by = id >> 5;
    int tx = tid & 31, ty = tid >> 5;   // 32 x 8
    int xx = bx * 32 + tx;
    int y0 = by * 32;
    for (int j = ty; j < 32; j += 8)
      tile[j][tx] = W_up[(size_t)(y0 + j) * DMODEL + xx];
    __syncthreads();
    int dd = tid >> 3;            // 0..31
    int c4 = (tid & 7) * 4;       // 0,4,...,28
    ushort4 o;
    o.x = f2bf(tile[c4 + 0][dd]);
    o.y = f2bf(tile[c4 + 1][dd]);
    o.z = f2bf(tile[c4 + 2][dd]);
    o.w = f2bf(tile[c4 + 3][dd]);
    *(ushort4*)(WupT + (size_t)(bx * 32 + dd) * DMODEL + y0 + c4) = o;
  }
}

// ---- mid2: gemm_wc (256 blocks, 64x64) + chunk-level scan (16 blocks) ------
__global__ __launch_bounds__(256) void mid2_kernel(
    const unsigned short* __restrict__ Wf_bf,
    const unsigned short* __restrict__ WupT,
    unsigned short* __restrict__ Wc,
    const float* __restrict__ carry, const float* __restrict__ cbeta,
    const float* __restrict__ dp,
    unsigned short* __restrict__ Pbf, float* __restrict__ pbeta) {
  __shared__ unsigned short As[3 * 64 * 64];   // 24 KB (ring-3)
  __shared__ unsigned short Bs[3 * 64 * 64];   // 24 KB
  int tid = threadIdx.x;
  if (blockIdx.x < 256) {
    int mt = blockIdx.x >> 4, nt = blockIdx.x & 15;
    f32x4 acc[2][2] = {};
    kloop64(Wf_bf, WupT, mt * 64, nt * 64, acc, As, Bs, tid);
    int lane = tid & 63, w = tid >> 6, wm = w & 1, wn = w >> 1;
    int quad = lane >> 4, l16 = lane & 15;
    #pragma unroll
    for (int j = 0; j < 2; ++j) {
      int col = nt * 64 + wn * 32 + j * 16 + l16;
      #pragma unroll
      for (int i = 0; i < 2; ++i) {
        int rowb = mt * 64 + wm * 32 + i * 16 + quad * 4;
        #pragma unroll
        for (int rr = 0; rr < 4; ++rr)
          Wc[(size_t)(rowb + rr) * DMODEL + col] = f2bf(acc[i][j][rr]);
      }
    }
  } else {
    float decay = sigmoid_dev(dp);
    float dL = powf(decay, (float)CHUNK);
    int gid = (blockIdx.x - 256) * 256 + tid;   // 0 .. 4095
    int b = gid >> 10, dd = gid & 1023;
    float P = 0.f;
    for (int c0 = 0; c0 < NCHUNK; c0 += 8) {
      float v[8];
      #pragma unroll
      for (int j = 0; j < 8; ++j)
        v[j] = carry[(size_t)(b * NCHUNK + c0 + j) * DMODEL + dd];
      #pragma unroll
      for (int j = 0; j < 8; ++j) {
        Pbf[(size_t)(b * NCHUNK + c0 + j) * DMODEL + dd] = f2bf(P);
        P = dL * P + v[j];
      }
    }
    if (dd == 0) {
      float Pb = 0.f;
      for (int c0 = 0; c0 < NCHUNK; c0 += 16) {
        float v[16];
        #pragma unroll
        for (int j = 0; j < 16; ++j) v[j] = cbeta[b * NCHUNK + c0 + j];
        #pragma unroll
        for (int j = 0; j < 16; ++j) {
          pbeta[b * NCHUNK + c0 + j] = Pb;
          Pb = dL * Pb + v[j];
        }
      }
    }
  }
}

// ---- main GEMM (fused with pout, r6 passing version) -----------------------
// out = hv@Wc^T + decay^(s+1)*(Pbf@Wc^T + pbeta*bb) + lbeta*bb + b_f
__global__ __launch_bounds__(512) void gemm_main(
    const unsigned short* __restrict__ A,    // hv (local scans) bf16 [16384][1024]
    const unsigned short* __restrict__ Bm,   // Wc bf16 [1024][1024] rows=e
    const unsigned short* __restrict__ Pbf,  // [512][1024] bf16 chunk-states
    const float* __restrict__ pbeta,
    const float* __restrict__ lbeta,
    const float* __restrict__ bb,
    const float* __restrict__ bias_f,
    const float* __restrict__ dp,
    float* __restrict__ out) {
  __shared__ unsigned short As[2 * 256 * 64];   // 64 KB (dbuf)
  __shared__ unsigned short Bs[2 * 256 * 64];   // 64 KB
  __shared__ unsigned short Ps[2 * 16 * 64];    // 4 KB (dbuf, 8 valid rows)
  __shared__ float dpow[CHUNK];
  const int TSLOT = 256 * 64;
  const int PSLOT = 16 * 64;
  int tid = threadIdx.x;
  if (tid < CHUNK) {
    float decay = sigmoid_dev(dp);
    dpow[tid] = powf(decay, (float)(tid + 1));
  }

  int lane = tid & 63, wid = tid >> 6;
  int wm = wid >> 2, wn = wid & 3;            // 2M x 4N waves
  int quad = lane >> 4, l16 = lane & 15;
  int r = tid >> 3, cch = tid & 7;            // staging: 64 rows x 8 chunks
  int g = cch ^ (r & 7);                      // pre-swizzled global chunk

  int bid = blockIdx.x;
  int xcd = bid & 7, jb = bid >> 3;
  int m0 = (xcd * 8 + (jb >> 2)) * 256;       // 64 m-tiles
  int n0 = (jb & 3) * 256;                    // 4 n-tiles
  int chunk0 = m0 >> 5;                       // first of this block's 8 chunks

  f32x4 acc[8][4] = {};
  f32x4 Pacc[4] = {};

  auto stageT = [&](int t, int p) {
    int k0 = t * 64;
    unsigned short* dA = As + p * TSLOT;
    unsigned short* dB = Bs + p * TSLOT;
    #pragma unroll
    for (int q = 0; q < 4; ++q)
      gl2lds16(A + (size_t)(m0 + q * 64 + r) * DMODEL + k0 + g * 8,
               dA + (q * 64 + r) * 64 + cch * 8);
    #pragma unroll
    for (int q = 0; q < 4; ++q)
      gl2lds16(Bm + (size_t)(n0 + q * 64 + r) * DMODEL + k0 + g * 8,
               dB + (q * 64 + r) * 64 + cch * 8);
    if (wid == 0) {
      int rp = lane >> 3, cp = lane & 7;
      int gp = cp ^ (rp & 7);
      gl2lds16(Pbf + (size_t)(chunk0 + rp) * DMODEL + k0 + gp * 8,
               Ps + p * PSLOT + lane * 8);
    }
  };
  auto compute = [&](int p) {
    const bf16x8* Av = (const bf16x8*)(As + p * TSLOT);
    const bf16x8* Bv = (const bf16x8*)(Bs + p * TSLOT);
    const bf16x8* Pv = (const bf16x8*)(Ps + p * PSLOT);
    #pragma unroll
    for (int kk = 0; kk < 2; ++kk) {
      bf16x8 bfr[4];
      #pragma unroll
      for (int j = 0; j < 4; ++j) {
        int rowB = wn * 64 + j * 16 + l16;
        bfr[j] = Bv[rowB * 8 + ((kk * 4 + quad) ^ (l16 & 7))];
      }
      bf16x8 pf = Pv[l16 * 8 + ((kk * 4 + quad) ^ (l16 & 7))];
      __builtin_amdgcn_s_setprio(1);
      #pragma unroll
      for (int j = 0; j < 4; ++j)
        Pacc[j] = __builtin_amdgcn_mfma_f32_16x16x32_bf16(pf, bfr[j], Pacc[j], 0, 0, 0);
      __builtin_amdgcn_s_setprio(0);
      #pragma unroll
      for (int i = 0; i < 8; ++i) {
        int rowA = wm * 128 + i * 16 + l16;
        bf16x8 af = Av[rowA * 8 + ((kk * 4 + quad) ^ (l16 & 7))];
        __builtin_amdgcn_s_setprio(1);
        #pragma unroll
        for (int j = 0; j < 4; ++j)
          acc[i][j] = __builtin_amdgcn_mfma_f32_16x16x32_bf16(af, bfr[j], acc[i][j], 0, 0, 0);
        __builtin_amdgcn_s_setprio(0);
      }
    }
  };

  stageT(0, 0);
  __syncthreads();

  for (int t = 0; t < 15; ++t) {
    int p = t & 1;
    stageT(t + 1, p ^ 1);
    compute(p);
    asm volatile("s_waitcnt vmcnt(0)" ::: "memory");
    __builtin_amdgcn_s_barrier();
    asm volatile("" ::: "memory");
  }
  compute(1);                                 // tile 15 (buf 1)

  float* Plds = (float*)As;                   // [8][256] f32 = 8 KB
  if (wm == 0 && quad < 2) {
    #pragma unroll
    for (int j = 0; j < 4; ++j)
      #pragma unroll
      for (int rr = 0; rr < 4; ++rr)
        Plds[(quad * 4 + rr) * 256 + wn * 64 + j * 16 + l16] = Pacc[j][rr];
  }
  __syncthreads();

  float bbv[4], bfv[4];
  #pragma unroll
  for (int j = 0; j < 4; ++j) {
    int col = n0 + wn * 64 + j * 16 + l16;
    bbv[j] = bb[col];
    bfv[j] = bias_f[col];
  }
  #pragma unroll
  for (int i = 0; i < 8; ++i) {
    int chl = wm * 4 + (i >> 1);              // this fragment's local chunk
    float pb = pbeta[chunk0 + chl];
    #pragma unroll
    for (int rr = 0; rr < 4; ++rr) {
      int row = m0 + wm * 128 + i * 16 + quad * 4 + rr;
      float lb  = lbeta[row];
      float dpw = dpow[row & 31];
      float* outRow = out + (size_t)row * DMODEL;
      #pragma unroll
      for (int j = 0; j < 4; ++j) {
        int col = n0 + wn * 64 + j * 16 + l16;
        float po = Plds[chl * 256 + wn * 64 + j * 16 + l16] + pb * bbv[j];
        outRow[col] = acc[i][j][rr] + dpw * po + lb * bbv[j] + bfv[j];
      }
    }
  }
}

// ---- launch ----------------------------------------------------------------

extern "C" void kernel_launch(void* const* d_in, const int* in_sizes, int n_in,
                              void* d_out, int out_size, void* d_ws, size_t ws_size,
                              hipStream_t stream) {
  const float* x    = (const float*)d_in[0];
  const float* mask = (const float*)d_in[1];
  const float* W_up = (const float*)d_in[2];
  const float* b_up = (const float*)d_in[3];
  const float* W_f  = (const float*)d_in[4];
  const float* b_f  = (const float*)d_in[5];
  const float* dp   = (const float*)d_in[6];
  float* out = (float*)d_out;

  char* ws = (char*)d_ws;
  unsigned short* hv    = (unsigned short*)(ws);                 // 32 MB
  unsigned short* Wc    = (unsigned short*)(ws + 33554432);      // 2 MB
  unsigned short* Wf_bf = (unsigned short*)(ws + 35651584);      // 2 MB
  unsigned short* WupT  = (unsigned short*)(ws + 37748736);      // 2 MB
  float* carry  = (float*)(ws + 39845888);                       // 2 MB
  unsigned short* Pbf = (unsigned short*)(ws + 41943040);        // 1 MB
  float* lbeta  = (float*)(ws + 45088768);                       // 64 KB
  float* cbeta  = (float*)(ws + 45154304);                       // 2 KB
  float* pbeta  = (float*)(ws + 45156352);                       // 2 KB
  float* bb     = (float*)(ws + 45158400);                       // 4 KB

  prep_scan<<<512, 256, 0, stream>>>(x, mask, dp, hv, carry, lbeta, cbeta);
  prep_misc<<<1280, 256, 0, stream>>>(W_up, b_up, W_f, Wf_bf, WupT, bb);
  mid2_kernel<<<272, 256, 0, stream>>>(Wf_bf, WupT, Wc, carry, cbeta, dp,
                                       Pbf, pbeta);
  gemm_main<<<256, 512, 0, stream>>>(hv, Wc, Pbf, pbeta, lbeta, bb, b_f, dp, out);
}